// Round 18
// baseline (257.647 us; speedup 1.0000x reference)
//
#include <hip/hip_runtime.h>

// Problem: N=32, C=512, H=W=32 (HW=1024), D=256.
// out = x + b_fuse + (Z P^T)/rowsum ; Z = W_fuse * V, P = exp(Q K^T/16).
//
// r18: WAVE SPECIALIZATION (producer-consumer) — the one untried mechanism.
//  k_attn14: 768 threads = 4 S-waves + 8 ZP-waves, 256 blocks (1/CU), 3 wv/SIMD.
//   q-tile 128 split into two 64-row halves; P double-buffered per half
//   (2 x [64][264] bf16). 9 half-steps: S-waves compute S/exp/psum for half s
//   into P[s&1] while ZP-waves multiply P[(s-1)&1] with Z. Roles have separate
//   loops (equal barrier counts) so accA (S) and accG (ZP) never coexist in
//   one wave -> no spills at the 170-reg/3-wave cap (r17's failure mode).
//
// Workspace (65 MB): [0,32MB) tp ; [32,64MB) Z ; [64MB,+512K) Wcat ; [+512K,+1MB) Wfuse

#define NB  32
#define CC  512
#define HWD 1024

typedef __attribute__((ext_vector_type(8))) short short8;
typedef __attribute__((ext_vector_type(4))) float f32x4;

__device__ __forceinline__ unsigned short f2bu(float f) {
    unsigned int u = __float_as_uint(f);
    u = (u + 0x7FFFu + ((u >> 16) & 1u)) >> 16;   // RNE to bf16
    return (unsigned short)u;
}

// ---------------- weights pack ----------------
__global__ __launch_bounds__(256) void k_packw(const float* __restrict__ Wt,
                                               const float* __restrict__ Wp,
                                               const float* __restrict__ Wf,
                                               unsigned short* __restrict__ Wcat,
                                               unsigned short* __restrict__ Wfuse) {
    int idx = blockIdx.x * 256 + threadIdx.x;       // 0 .. 262143
    int o = idx >> 9;
    float cv = (o < 256) ? Wt[idx] : Wp[idx - 131072];
    Wcat[idx]  = f2bu(cv);
    Wfuse[idx] = f2bu(Wf[idx]);
}

// ---------------- merged GEMM: embed (y<2) / Z (y>=2) [r8 proven] ----------------
__global__ __launch_bounds__(512) void k_mm(const float* __restrict__ x,
                                            const unsigned short* __restrict__ Wcat,
                                            const unsigned short* __restrict__ Wfuse,
                                            const float* __restrict__ bt,
                                            const float* __restrict__ bp,
                                            unsigned short* __restrict__ tp,
                                            unsigned short* __restrict__ Z) {
    __shared__ __align__(16) float Tr[32 * 132];                 // 16896 B
    __shared__ __align__(16) unsigned short As[128 * 40];        // 10240 B
    __shared__ __align__(16) unsigned short Bs[256 * 40];        // 20480 B
    const int m0 = blockIdx.x << 7;
    const int yb = blockIdx.y;
    const bool isZ = (yb >= 2);
    const int n0 = (yb & 1) << 8;
    const unsigned short* W = isZ ? Wfuse : Wcat;
    const int n  = m0 >> 10, qbase = m0 & 1023;
    const int t = threadIdx.x, lane = t & 63, wave = t >> 6;
    const int wr = wave >> 2, wc = wave & 3;
    const int lrow = lane & 15, hi = lane >> 4, lhk = hi << 3;
    const f32x4 fz = {0.f, 0.f, 0.f, 0.f};
    f32x4 acc[4][4];
#pragma unroll
    for (int i = 0; i < 4; ++i)
#pragma unroll
        for (int j = 0; j < 4; ++j) acc[i][j] = fz;

    const int tr_r = t >> 4, tr_q = (t & 15) << 3;
    const int p2_pix = t & 127, p2_c = (t >> 7) << 3;

    for (int kt = 0; kt < 16; ++kt) {
        const int k0 = kt << 5;
        {
            const float* src = x + ((size_t)(n * CC + k0 + tr_r)) * HWD + qbase + tr_q;
            float4 v0 = *(const float4*)(src);
            float4 v1 = *(const float4*)(src + 4);
            *(float4*)(Tr + tr_r * 132 + tr_q) = v0;
            *(float4*)(Tr + tr_r * 132 + tr_q + 4) = v1;
#pragma unroll
            for (int i = 0; i < 2; ++i) {
                int chunk = t + (i << 9);
                int r = chunk >> 2, ko = (chunk & 3) << 3;
                *(uint4*)(Bs + r * 40 + ko) =
                    *(const uint4*)(W + ((size_t)(n0 + r)) * CC + k0 + ko);
            }
        }
        __syncthreads();
        {
            short8 o8;
#pragma unroll
            for (int j = 0; j < 8; ++j)
                o8[j] = (short)f2bu(Tr[(p2_c + j) * 132 + p2_pix]);
            *(short8*)(As + p2_pix * 40 + p2_c) = o8;
        }
        __syncthreads();
        short8 af[4], bfm[4];
#pragma unroll
        for (int mi = 0; mi < 4; ++mi)
            af[mi] = *(const short8*)(As + (wr * 64 + mi * 16 + lrow) * 40 + lhk);
#pragma unroll
        for (int ni = 0; ni < 4; ++ni)
            bfm[ni] = *(const short8*)(Bs + (wc * 64 + ni * 16 + lrow) * 40 + lhk);
#pragma unroll
        for (int mi = 0; mi < 4; ++mi)
#pragma unroll
            for (int ni = 0; ni < 4; ++ni)
                acc[mi][ni] = __builtin_amdgcn_mfma_f32_16x16x32_bf16(
                    af[mi], bfm[ni], acc[mi][ni], 0, 0, 0);
        __syncthreads();
    }
    if (!isZ) {
#pragma unroll
        for (int ni = 0; ni < 4; ++ni) {
            const int col = n0 + wc * 64 + ni * 16 + lrow;
            const float bias = (col < 256) ? bt[col] : bp[col - 256];
#pragma unroll
            for (int mi = 0; mi < 4; ++mi)
#pragma unroll
                for (int j = 0; j < 4; ++j) {
                    const int row = m0 + wr * 64 + mi * 16 + hi * 4 + j;
                    tp[(size_t)row * CC + col] = f2bu(acc[mi][ni][j] + bias);
                }
        }
    } else {
        const int kbase = qbase + wr * 64;
        unsigned short* Zn = Z + (size_t)n * CC * HWD;
#pragma unroll
        for (int ni = 0; ni < 4; ++ni) {
            const int o = n0 + wc * 64 + ni * 16 + lrow;
#pragma unroll
            for (int mi = 0; mi < 4; ++mi) {
                ushort4 v;
                v.x = f2bu(acc[mi][ni][0]);
                v.y = f2bu(acc[mi][ni][1]);
                v.z = f2bu(acc[mi][ni][2]);
                v.w = f2bu(acc[mi][ni][3]);
                *(ushort4*)(Zn + (size_t)o * HWD + kbase + mi * 16 + (hi << 2)) = v;
            }
        }
    }
}

// ---------------- attention: wave-specialized producer-consumer ----------------
// 12 waves: 0-3 produce P (S phase), 4-11 consume (ZP phase). 256 blocks = 1/CU.
__global__ __launch_bounds__(768, 3) void k_attn14(const unsigned short* __restrict__ tp,
                                                   const unsigned short* __restrict__ Z,
                                                   const float* __restrict__ bfu,
                                                   const float* __restrict__ x,
                                                   float* __restrict__ out) {
    constexpr int QST = 264;
    constexpr int PST = 264;
    constexpr int QSZ = 128 * QST;                 // 33792 elems
    constexpr int PHSZ = 64 * PST;                 // 16896 elems (one q-half)
    __shared__ __align__(16) unsigned short SL[QSZ + 2 * PHSZ];  // 135,168 B
    __shared__ float rowsum[128];
    unsigned short* Qs = SL;                       // [128][264]
    unsigned short* Pbufs = SL + QSZ;              // 2 x [64][264]

    const int b = blockIdx.x;
    const int n = b & 31;                          // XCD = n % 8 -> 4 batches/XCD
    const int q0 = (b >> 5) << 7;
    const int t = threadIdx.x, lane = t & 63, wave = t >> 6;   // wave 0..11
    const int lrow = lane & 15, hi = lane >> 4, lhk = hi << 3;
    const f32x4 fz = {0.f, 0.f, 0.f, 0.f};

    const unsigned short* tpn = tp + (size_t)n * HWD * CC;
    const unsigned short* Zn  = Z + (size_t)n * CC * HWD;

    if (t < 128) rowsum[t] = 0.f;
    // stage Q tile: 4096 short8 chunks over 768 threads (6 passes, guarded)
    for (int pass = 0; pass < 6; ++pass) {
        int chunk = pass * 768 + t;
        if (chunk < 4096) {
            int row = chunk >> 5, co = (chunk & 31) << 3;
            *(short8*)(Qs + row * QST + co) =
                *(const short8*)(tpn + (size_t)(q0 + row) * CC + co);
        }
    }
    __syncthreads();

    if (wave < 4) {
        // ================= S role: produce P for half-step s =================
        const int ksb = wave << 6;                 // this wave's 64-key segment
        for (int s = 0; s < 9; ++s) {
            if (s < 8) {
                const int it = s >> 1, qh = s & 1;
                const int kv0 = it << 8, qh0 = qh << 6;
                unsigned short* Pb = Pbufs + (s & 1) * PHSZ;
                f32x4 accA[4][4];                  // [qj][kc] : 64q x 64k
#pragma unroll
                for (int qj = 0; qj < 4; ++qj)
#pragma unroll
                    for (int kc = 0; kc < 4; ++kc) accA[qj][kc] = fz;
#pragma unroll
                for (int kt = 0; kt < 8; ++kt) {
                    const int d0 = (kt << 5) + lhk;
                    short8 kf[4];
#pragma unroll
                    for (int kc = 0; kc < 4; ++kc)
                        kf[kc] = *(const short8*)(tpn +
                            (size_t)(kv0 + ksb + kc * 16 + lrow) * CC + 256 + d0);
#pragma unroll
                    for (int qj = 0; qj < 4; ++qj) {
                        short8 qfr = *(const short8*)(Qs + (qh0 + qj * 16 + lrow) * QST + d0);
#pragma unroll
                        for (int kc = 0; kc < 4; ++kc)
                            accA[qj][kc] = __builtin_amdgcn_mfma_f32_16x16x32_bf16(
                                qfr, kf[kc], accA[qj][kc], 0, 0, 0);
                    }
                }
                float psum[4][4];
#pragma unroll
                for (int qj = 0; qj < 4; ++qj)
#pragma unroll
                    for (int j = 0; j < 4; ++j) psum[qj][j] = 0.f;
#pragma unroll
                for (int qj = 0; qj < 4; ++qj)
#pragma unroll
                    for (int kc = 0; kc < 4; ++kc)
#pragma unroll
                        for (int j = 0; j < 4; ++j) {
                            float p = __expf(accA[qj][kc][j] * 0.0625f);
                            psum[qj][j] += p;
                            Pb[(qj * 16 + hi * 4 + j) * PST + ksb + kc * 16 + lrow] = f2bu(p);
                        }
#pragma unroll
                for (int qj = 0; qj < 4; ++qj)
#pragma unroll
                    for (int j = 0; j < 4; ++j) {
                        float sv = psum[qj][j];
                        sv += __shfl_xor(sv, 1, 16);
                        sv += __shfl_xor(sv, 2, 16);
                        sv += __shfl_xor(sv, 4, 16);
                        sv += __shfl_xor(sv, 8, 16);
                        if (lrow == 0)
                            atomicAdd(&rowsum[qh0 + qj * 16 + hi * 4 + j], sv);
                    }
            }
            __syncthreads();
        }
        // S waves exit (9 barriers total after staging barrier)
    } else {
        // ================= ZP role: consume P, accumulate accG =================
        const int ob = (wave - 4) << 6;            // wave's 64-output (o) range
        f32x4 accG[8][4];                          // [qj global][mi]
#pragma unroll
        for (int qj = 0; qj < 8; ++qj)
#pragma unroll
            for (int mi = 0; mi < 4; ++mi) accG[qj][mi] = fz;

        for (int s = 0; s < 9; ++s) {
            if (s >= 1) {
                const int sp = s - 1, it = sp >> 1;
                const int kv0 = it << 8;
                const unsigned short* Pb = Pbufs + (sp & 1) * PHSZ;
                __builtin_amdgcn_s_setprio(1);
                if ((sp & 1) == 0) {               // q rows 0..63 -> accG[0..3]
#pragma unroll
                    for (int ks = 0; ks < 8; ++ks) {
                        const int kb = (ks << 5) + lhk;
                        short8 zf[4];
#pragma unroll
                        for (int mi = 0; mi < 4; ++mi)
                            zf[mi] = *(const short8*)(Zn +
                                (size_t)(ob + mi * 16 + lrow) * HWD + kv0 + kb);
#pragma unroll
                        for (int qjh = 0; qjh < 4; ++qjh) {
                            short8 pa = *(const short8*)(Pb + (qjh * 16 + lrow) * PST + kb);
#pragma unroll
                            for (int mi = 0; mi < 4; ++mi)
                                accG[qjh][mi] = __builtin_amdgcn_mfma_f32_16x16x32_bf16(
                                    pa, zf[mi], accG[qjh][mi], 0, 0, 0);
                        }
                    }
                } else {                            // q rows 64..127 -> accG[4..7]
#pragma unroll
                    for (int ks = 0; ks < 8; ++ks) {
                        const int kb = (ks << 5) + lhk;
                        short8 zf[4];
#pragma unroll
                        for (int mi = 0; mi < 4; ++mi)
                            zf[mi] = *(const short8*)(Zn +
                                (size_t)(ob + mi * 16 + lrow) * HWD + kv0 + kb);
#pragma unroll
                        for (int qjh = 0; qjh < 4; ++qjh) {
                            short8 pa = *(const short8*)(Pb + (qjh * 16 + lrow) * PST + kb);
#pragma unroll
                            for (int mi = 0; mi < 4; ++mi)
                                accG[4 + qjh][mi] = __builtin_amdgcn_mfma_f32_16x16x32_bf16(
                                    pa, zf[mi], accG[4 + qjh][mi], 0, 0, 0);
                        }
                    }
                }
                __builtin_amdgcn_s_setprio(0);
            }
            __syncthreads();
        }
        // ---- epilogue (ZP waves only): out = x + b + accG / rowsum ----
        float bias[4];
#pragma unroll
        for (int mi = 0; mi < 4; ++mi) bias[mi] = bfu[ob + mi * 16 + lrow];
#pragma unroll
        for (int qj = 0; qj < 8; ++qj) {
            const float4 rs = *(const float4*)&rowsum[qj * 16 + (hi << 2)];
            float4 inv4;
            inv4.x = 1.f / rs.x; inv4.y = 1.f / rs.y;
            inv4.z = 1.f / rs.z; inv4.w = 1.f / rs.w;
#pragma unroll
            for (int mi = 0; mi < 4; ++mi) {
                const int o = ob + mi * 16 + lrow;
                const size_t idx = ((size_t)(n * CC + o)) * HWD + q0 + qj * 16 + (hi << 2);
                const float4 xr = *(const float4*)(x + idx);
                float4 r;
                r.x = accG[qj][mi][0] * inv4.x + bias[mi] + xr.x;
                r.y = accG[qj][mi][1] * inv4.y + bias[mi] + xr.y;
                r.z = accG[qj][mi][2] * inv4.z + bias[mi] + xr.z;
                r.w = accG[qj][mi][3] * inv4.w + bias[mi] + xr.w;
                *(float4*)(out + idx) = r;
            }
        }
    }
}

extern "C" void kernel_launch(void* const* d_in, const int* in_sizes, int n_in,
                              void* d_out, int out_size, void* d_ws, size_t ws_size,
                              hipStream_t stream) {
    const float* x  = (const float*)d_in[0];
    const float* Wt = (const float*)d_in[1];
    const float* bt = (const float*)d_in[2];
    const float* Wp = (const float*)d_in[3];
    const float* bp = (const float*)d_in[4];
    const float* Wf = (const float*)d_in[5];
    const float* bfu = (const float*)d_in[6];
    float* out = (float*)d_out;

    char* ws = (char*)d_ws;
    unsigned short* tp    = (unsigned short*)(ws);                 // 32 MB
    unsigned short* Z     = (unsigned short*)(ws + 33554432);      // 32 MB
    unsigned short* Wcat  = (unsigned short*)(ws + 67108864);      // 512 KB
    unsigned short* Wfuse = (unsigned short*)(ws + 67633152);      // 512 KB

    k_packw <<<dim3(1024), 256, 0, stream>>>(Wt, Wp, Wf, Wcat, Wfuse);
    k_mm    <<<dim3(256, 4), 512, 0, stream>>>(x, Wcat, Wfuse, bt, bp, tp, Z);
    k_attn14<<<dim3(256), 768, 0, stream>>>(tp, Z, bfu, x, out);
}